// Round 11
// baseline (103.832 us; speedup 1.0000x reference)
//
#include <hip/hip_runtime.h>
#include <hip/hip_bf16.h>
#include <cstdint>

#define DEVFN __device__ __forceinline__

namespace {

constexpr int B = 16, T = 8192, C = 128, H = 128, K = 5;
constexpr int TP1 = T + 1;                      // 8193 slots (slot 0 = init row)
constexpr int N = B * TP1 * H;                  // 16,779,264
constexpr int NKK = 20;                         // (C*K)/32 K-steps
constexpr int NCH = T / 64;                     // 128 chunks over slots [1+64j, 64+64j]
constexpr int NSER = B * H;                     // 2048 scan series
constexpr int WF_ELE = NKK * 8 * 64 * 2 * 8;    // bf16 fragment elems (F+Z interleaved)
constexpr int XPITCH = 136;                     // LDS row pitch in shorts (272 B = 17*16B)

typedef __attribute__((ext_vector_type(8))) short short8;
typedef __attribute__((ext_vector_type(4))) float f32x4;

DEVFN float sigmoidf(float x) { return 1.0f / (1.0f + __expf(-x)); }
DEVFN unsigned bfb(float v) {
  __hip_bfloat16 h = __float2bfloat16(v);
  return (unsigned)*reinterpret_cast<unsigned short*>(&h);
}

// Segment-summary compose: L=[..b] then R=[b+1..]:
//   P* = P*_L * Fl_L * P*_R ; Q = Fl_L * P*_R * Q_L + Q_R ; Fl = Fl_R
DEVFN void compose(float& P, float& Q, float& Fl, float Pr, float Qr, float Flr) {
  float t = Fl * Pr;
  P = P * t;
  Q = fmaf(t, Q, Qr);
  Fl = Flr;
}

// ---------------------------------------------------------------------------
// Weights (H,C,K) f32 -> MFMA B-fragment layout bf16 (16x16x32), F/Z interleaved:
//   idx = (((kk*8 + nf8)*64 + lane)*2 + fz)*8 + j
//   value = Bmat[kdim = kk*32 + (lane>>4)*8 + j][h = nf8*16 + (lane&15)]
__global__ __launch_bounds__(256)
void wprep_kernel(const float* __restrict__ fw, const float* __restrict__ zw,
                  short* __restrict__ Wfrag) {
  int idx = blockIdx.x * 256 + threadIdx.x;
  if (idx >= WF_ELE) return;
  int j = idx & 7;
  int fz = (idx >> 3) & 1;
  int lane = (idx >> 4) & 63;
  int nf8 = (idx >> 10) & 7;
  int kk = idx >> 13;
  int kdim = kk * 32 + ((lane >> 4) << 3) + j;
  int h = nf8 * 16 + (lane & 15);
  int k = kdim >> 7, c = kdim & 127;
  int src = (h * C + c) * K + k;
  float w = fz ? zw[src] : fw[src];
  Wfrag[idx] = (short)bfb(w);
}

// ---------------------------------------------------------------------------
// Conv via MFMA + in-epilogue chunk summaries.
// Round-11 geometry: 4 waves x 32 h-cols/wave (F+Z for 2 h-groups) -> each
// LDS a-frag read feeds 4 MFMAs (halves the dominant LDS-read pipe, 25.6 ->
// 12.8 us/CU) with NO weight duplication. r2 tried this and spilled at the
// (256,4) 128-reg cap; here __launch_bounds__(256,2) gives the 256-reg class
// (2 waves/SIMD, 2 blocks/CU): 64 acc + 64 w + 32 a + ~20 misc ~= 180 regs,
// spill-free by construction. K-loop keeps the r6 sched_barrier-pinned
// pipeline: weights depth-3 in 4 rotating buffers, a-frags 1-ahead dbuf.
__global__ __launch_bounds__(256, 2)
void conv_mfma_kernel(const float* __restrict__ x,
                      const float* __restrict__ fb, const float* __restrict__ zb,
                      const short* __restrict__ Wfrag,
                      unsigned* __restrict__ FG,
                      float* __restrict__ sumP, float* __restrict__ sumQ) {
  __shared__ short xs[68 * XPITCH];  // rows r <-> t = t0-2+r; 272B pitch
  const int b = blockIdx.y;
  const int t0 = blockIdx.x * 64;
  const int tid = threadIdx.x;
  const int lane = tid & 63;
  const int wid = tid >> 6;          // 0..3 = 32-wide h-col group
  const int lrow = lane & 15;
  const int lg = lane >> 4;

  // ---- stage x tile as bf16 (68 rows x 128 c), linear padded layout ----
  for (int i = tid; i < 68 * 16; i += 256) {
    int r = i >> 4, co = (i & 15) << 3;
    int t = t0 - 2 + r;
    f32x4 v0 = {0.f, 0.f, 0.f, 0.f}, v1 = v0;
    if (t >= 0 && t < T) {
      const f32x4* p = reinterpret_cast<const f32x4*>(x + ((size_t)(b * T + t)) * C + co);
      v0 = p[0]; v1 = p[1];
    }
    short8 s;
    s[0] = (short)bfb(v0[0]); s[1] = (short)bfb(v0[1]); s[2] = (short)bfb(v0[2]); s[3] = (short)bfb(v0[3]);
    s[4] = (short)bfb(v1[0]); s[5] = (short)bfb(v1[1]); s[6] = (short)bfb(v1[2]); s[7] = (short)bfb(v1[3]);
    *reinterpret_cast<short8*>(xs + r * XPITCH + co) = s;
  }
  __syncthreads();

  f32x4 accF0[4], accZ0[4], accF1[4], accZ1[4];
#pragma unroll
  for (int mf = 0; mf < 4; ++mf) {
    accF0[mf] = {0.f,0.f,0.f,0.f}; accZ0[mf] = {0.f,0.f,0.f,0.f};
    accF1[mf] = {0.f,0.f,0.f,0.f}; accZ1[mf] = {0.f,0.f,0.f,0.f};
  }

  const char* xsb = reinterpret_cast<const char*>(xs);
  // s8 index: kk*1024 + nf8*128 + lane*2 + fz ; wave wid uses nf8 = 2wid, 2wid+1
  const short8* wb = reinterpret_cast<const short8*>(Wfrag) + (wid * 256 + lane * 2);
  const int abase = lrow * 272 + lg * 16;

  // ---- software-pipelined K-loop (sched_barrier-pinned) ----
  short8 wf0[4], wz0[4], wf1[4], wz1[4], av[2][4];
#pragma unroll
  for (int p = 0; p < 3; ++p) {            // weights for kk=0,1,2
    const int o = p * 1024;
    wf0[p] = wb[o];       wz0[p] = wb[o + 1];
    wf1[p] = wb[o + 128]; wz1[p] = wb[o + 129];
  }
#pragma unroll
  for (int mf = 0; mf < 4; ++mf)           // a-frags for kk=0 (k=0, cq=0)
    av[0][mf] = *reinterpret_cast<const short8*>(xsb + (abase + (mf * 16) * 272));

#pragma unroll
  for (int kk = 0; kk < NKK; ++kk) {
    __builtin_amdgcn_sched_barrier(0);     // fence: keep prefetch cluster here
    if (kk + 3 < NKK) {                    // weight prefetch, 3 iters ahead
      const int o = (kk + 3) * 1024;
      const int r3 = (kk + 3) & 3;
      wf0[r3] = wb[o];       wz0[r3] = wb[o + 1];
      wf1[r3] = wb[o + 128]; wz1[r3] = wb[o + 129];
    }
    if (kk + 1 < NKK) {                    // a-frag prefetch, 1 iter ahead
      const int k1 = (kk + 1) >> 2;        // compile-time
      const int cq1 = ((kk + 1) & 3) << 6; // compile-time
#pragma unroll
      for (int mf = 0; mf < 4; ++mf)
        av[(kk + 1) & 1][mf] =
            *reinterpret_cast<const short8*>(xsb + (abase + (mf * 16 + k1) * 272 + cq1));
    }
    __builtin_amdgcn_sched_barrier(0);     // fence: loads cannot sink past MFMAs
    const int r = kk & 3, ab = kk & 1;
#pragma unroll
    for (int mf = 0; mf < 4; ++mf) {
      accF0[mf] = __builtin_amdgcn_mfma_f32_16x16x32_bf16(av[ab][mf], wf0[r], accF0[mf], 0, 0, 0);
      accZ0[mf] = __builtin_amdgcn_mfma_f32_16x16x32_bf16(av[ab][mf], wz0[r], accZ0[mf], 0, 0, 0);
      accF1[mf] = __builtin_amdgcn_mfma_f32_16x16x32_bf16(av[ab][mf], wf1[r], accF1[mf], 0, 0, 0);
      accZ1[mf] = __builtin_amdgcn_mfma_f32_16x16x32_bf16(av[ab][mf], wz1[r], accZ1[mf], 0, 0, 0);
    }
  }

  // ---- epilogue: FG stores + chunk summaries for both h-groups ----
  const int cblk = blockIdx.x;
  const int h0 = wid * 32 + lrow, h1 = h0 + 16;
  const float bF0 = fb[h0], bZ0 = zb[h0], bF1 = fb[h1], bZ1 = zb[h1];
  float cP0 = 1.f, cQ0 = 0.f, cFl0 = 1.f;
  float cP1 = 1.f, cQ1 = 0.f, cFl1 = 1.f;
#pragma unroll
  for (int mf = 0; mf < 4; ++mf) {
    float y0 = 0.f, P0 = 1.f, pF0 = 1.f;
    float y1 = 0.f, P1 = 1.f, pF1 = 1.f;
#pragma unroll
    for (int j = 0; j < 4; ++j) {
      int m = mf * 16 + lg * 4 + j;
      int s = t0 + m + 1;                       // gate-slot index
      size_t off = (size_t)(b * TP1 + s) * H;
      float F0 = sigmoidf(accF0[mf][j] + bF0);
      float G0 = sigmoidf(accZ0[mf][j] + bZ0) * (1.0f - F0);
      float F1 = sigmoidf(accF1[mf][j] + bF1);
      float G1 = sigmoidf(accZ1[mf][j] + bZ1) * (1.0f - F1);
      FG[off + h0] = bfb(F0) | (bfb(G0) << 16);
      FG[off + h1] = bfb(F1) | (bfb(G1) << 16);
      if (j == 0) { y0 = G0; y1 = G1; }
      else {
        P0 *= pF0; y0 = fmaf(pF0, y0, G0);
        P1 *= pF1; y1 = fmaf(pF1, y1, G1);
      }
      pF0 = F0; pF1 = F1;
    }
    // compose across lg (4 groups of 4 rows) — 2-level tree, valid on lg==0
    float tP0 = P0, tQ0 = y0, tF0 = pF0;
    float tP1 = P1, tQ1 = y1, tF1 = pF1;
    {
      float q, r0, s0, r1, s1;
      q = __shfl(tP0, lane + 16, 64); r0 = __shfl(tQ0, lane + 16, 64); s0 = __shfl(tF0, lane + 16, 64);
      compose(tP0, tQ0, tF0, q, r0, s0);
      q = __shfl(tP1, lane + 16, 64); r1 = __shfl(tQ1, lane + 16, 64); s1 = __shfl(tF1, lane + 16, 64);
      compose(tP1, tQ1, tF1, q, r1, s1);
      q = __shfl(tP0, lane + 32, 64); r0 = __shfl(tQ0, lane + 32, 64); s0 = __shfl(tF0, lane + 32, 64);
      compose(tP0, tQ0, tF0, q, r0, s0);
      q = __shfl(tP1, lane + 32, 64); r1 = __shfl(tQ1, lane + 32, 64); s1 = __shfl(tF1, lane + 32, 64);
      compose(tP1, tQ1, tF1, q, r1, s1);
    }
    if (mf == 0) { cP0 = tP0; cQ0 = tQ0; cFl0 = tF0; cP1 = tP1; cQ1 = tQ1; cFl1 = tF1; }
    else { compose(cP0, cQ0, cFl0, tP0, tQ0, tF0); compose(cP1, cQ1, cFl1, tP1, tQ1, tF1); }
  }
  if (lg == 0) {
    int sbase = cblk * NSER + b * H;
    sumP[sbase + h0] = cP0; sumQ[sbase + h0] = cQ0;
    sumP[sbase + h1] = cP1; sumQ[sbase + h1] = cQ1;
  }
}

// ---------------------------------------------------------------------------
// scanB: init row (slot 0) + sequential chain over chunk summaries.
// Only 2048 threads exist (no TLP) -> batch 8 iterations' independent loads
// ahead of the serial compose chain (24 loads in flight).
__global__ void scanB_kernel(const float* __restrict__ init,
                             const unsigned* __restrict__ FG_r,
                             unsigned* __restrict__ FG_w,
                             const float* __restrict__ sumQ,
                             float* __restrict__ sumP_cin,   // in: P*, out: cin
                             float* __restrict__ out) {
  int g = blockIdx.x * blockDim.x + threadIdx.x;   // 0..NSER-1 = b*128+h
  int b = g >> 7, h = g & (H - 1);
  float rf = init[g];
  float rz = init[NSER + g];
  float F0 = sigmoidf(rf), z = sigmoidf(rz);
  float G0 = z * (1.0f - F0);
  size_t base = (size_t)b * TP1 * H + h;
  FG_w[base] = bfb(F0) | (bfb(G0) << 16);
  out[base] = G0;
  float y = G0;        // y[0]
  float Fp = F0;       // F[slot 64j] entering group
  for (int j0 = 0; j0 < NCH; j0 += 8) {
    float ps[8], qs[8], fl[8];
#pragma unroll
    for (int u = 0; u < 8; ++u) {
      int sidx = (j0 + u) * NSER + g;
      ps[u] = sumP_cin[sidx];
      qs[u] = sumQ[sidx];
      int jn = j0 + u + 1;
      fl[u] = (jn < NCH)
                  ? __uint_as_float(FG_r[base + (size_t)(64 * jn) * H] << 16)
                  : 1.0f;
    }
#pragma unroll
    for (int u = 0; u < 8; ++u) {
      sumP_cin[(j0 + u) * NSER + g] = y;        // cin for chunk j0+u
      y = fmaf(Fp * ps[u], y, qs[u]);           // y[64(j0+u+1)]
      Fp = fl[u];
    }
  }
}

// ---------------------------------------------------------------------------
// scanC: chunk j covers slots [1+64j, 64+64j]; local rescan with carry-in.
// Keep max TLP (2048 blocks); r9 proved wider per-thread loads lose here.
__global__ __launch_bounds__(128)
void scanC_kernel(const unsigned* __restrict__ FG, const float* __restrict__ cin,
                  float* __restrict__ out) {
  const int b = blockIdx.y, j = blockIdx.x, h = threadIdx.x;
  const int s0 = 1 + j * 64;
  float y = cin[j * NSER + b * H + h];
  const size_t base = (size_t)b * TP1 * H + h;
  const unsigned* p = FG + base + (size_t)s0 * H;
  float Fprev = __uint_as_float(p[-H] << 16);     // F[64j]
  float* po = out + base + (size_t)s0 * H;
#pragma unroll 8
  for (int t = 0; t < 64; ++t) {
    unsigned u = *p; p += H;
    float G = __uint_as_float(u & 0xffff0000u);
    y = fmaf(Fprev, y, G);
    Fprev = __uint_as_float(u << 16);
    *po = y; po += H;
  }
}

}  // namespace

// ---------------------------------------------------------------------------
extern "C" void kernel_launch(void* const* d_in, const int* in_sizes, int n_in,
                              void* d_out, int out_size, void* d_ws, size_t ws_size,
                              hipStream_t stream) {
  const float* x    = (const float*)d_in[0];
  const float* init = (const float*)d_in[1];
  const float* zw   = (const float*)d_in[2];
  const float* zb   = (const float*)d_in[3];
  const float* fw   = (const float*)d_in[4];
  const float* fb   = (const float*)d_in[5];
  float* out = (float*)d_out;
  char* ws = (char*)d_ws;

  // ws layout: [0,4N) FG; then sumP (1MB, becomes cin), sumQ (1MB), Wfrag (0.33MB).
  unsigned* FG = (unsigned*)ws;
  float* sumP = (float*)(ws + (size_t)N * 4);
  float* sumQ = sumP + (size_t)NCH * NSER;
  short* Wfrag = (short*)(sumQ + (size_t)NCH * NSER);

  wprep_kernel<<<(WF_ELE + 255) / 256, 256, 0, stream>>>(fw, zw, Wfrag);
  conv_mfma_kernel<<<dim3(NCH, B), 256, 0, stream>>>(x, fb, zb, Wfrag, FG, sumP, sumQ);
  scanB_kernel<<<16, 128, 0, stream>>>(init, FG, FG, sumQ, sumP, out);
  scanC_kernel<<<dim3(NCH, B), 128, 0, stream>>>(FG, sumP, out);
}

// Round 12
// 100.302 us; speedup vs baseline: 1.0352x; 1.0352x over previous
//
#include <hip/hip_runtime.h>
#include <hip/hip_bf16.h>
#include <cstdint>

#define DEVFN __device__ __forceinline__

namespace {

constexpr int B = 16, T = 8192, C = 128, H = 128, K = 5;
constexpr int TP1 = T + 1;                      // 8193 slots (slot 0 = init row)
constexpr int N = B * TP1 * H;                  // 16,779,264
constexpr int NKK = 20;                         // (C*K)/32 K-steps
constexpr int NCH = T / 64;                     // 128 chunks over slots [1+64j, 64+64j]
constexpr int NSER = B * H;                     // 2048 scan series
constexpr int WF_ELE = NKK * 8 * 64 * 2 * 8;    // bf16 fragment elems (F+Z interleaved)
constexpr int XPITCH = 136;                     // LDS row pitch in shorts (272 B = 17*16B)

typedef __attribute__((ext_vector_type(8))) short short8;
typedef __attribute__((ext_vector_type(4))) float f32x4;

DEVFN float sigmoidf(float x) { return 1.0f / (1.0f + __expf(-x)); }
DEVFN unsigned bfb(float v) {
  __hip_bfloat16 h = __float2bfloat16(v);
  return (unsigned)*reinterpret_cast<unsigned short*>(&h);
}

// Segment-summary compose: L=[..b] then R=[b+1..]:
//   P* = P*_L * Fl_L * P*_R ; Q = Fl_L * P*_R * Q_L + Q_R ; Fl = Fl_R
DEVFN void compose(float& P, float& Q, float& Fl, float Pr, float Qr, float Flr) {
  float t = Fl * Pr;
  P = P * t;
  Q = fmaf(t, Q, Qr);
  Fl = Flr;
}

// ---------------------------------------------------------------------------
// Weights (H,C,K) f32 -> MFMA B-fragment layout bf16 (16x16x32), F/Z interleaved:
//   idx = (((kk*8 + nf8)*64 + lane)*2 + fz)*8 + j
//   value = Bmat[kdim = kk*32 + (lane>>4)*8 + j][h = nf8*16 + (lane&15)]
__global__ __launch_bounds__(256)
void wprep_kernel(const float* __restrict__ fw, const float* __restrict__ zw,
                  short* __restrict__ Wfrag) {
  int idx = blockIdx.x * 256 + threadIdx.x;
  if (idx >= WF_ELE) return;
  int j = idx & 7;
  int fz = (idx >> 3) & 1;
  int lane = (idx >> 4) & 63;
  int nf8 = (idx >> 10) & 7;
  int kk = idx >> 13;
  int kdim = kk * 32 + ((lane >> 4) << 3) + j;
  int h = nf8 * 16 + (lane & 15);
  int k = kdim >> 7, c = kdim & 127;
  int src = (h * C + c) * K + k;
  float w = fz ? zw[src] : fw[src];
  Wfrag[idx] = (short)bfb(w);
}

// ---------------------------------------------------------------------------
// Conv via MFMA + in-epilogue chunk summaries (round-6/10 best, verbatim).
// Plateau evidence (r1-r11): LDS-read halving (r11: conflicts 5.24M->2.62M,
// VGPR 88, no spill -- and dur FLAT, occupancy 34->19%), weight-stream
// halving (r3), 8 waves/SIMD (r4: spills at 32 VGPR), deep weight pipeline
// (r5/r6: +3us, kept), grid fusion (r7 lookback / r8 cooperative: both
// catastrophic). The (per-wave working set x waves/SIMD) product is pinned
// by the 64/128/256 allocation quanta; measured configs on both sides of
// the trade land at ~66-69us. This geometry is the empirical optimum.
__global__ __launch_bounds__(512, 4)
void conv_mfma_kernel(const float* __restrict__ x,
                      const float* __restrict__ fb, const float* __restrict__ zb,
                      const short* __restrict__ Wfrag,
                      unsigned* __restrict__ FG,
                      float* __restrict__ sumP, float* __restrict__ sumQ) {
  __shared__ short xs[68 * XPITCH];  // rows r <-> t = t0-2+r; 272B pitch
  const int b = blockIdx.y;
  const int t0 = blockIdx.x * 64;
  const int tid = threadIdx.x;
  const int lane = tid & 63;
  const int wid = tid >> 6;          // 0..7 = h-col group
  const int lrow = lane & 15;
  const int lg = lane >> 4;

  // ---- stage x tile as bf16 (68 rows x 128 c), linear padded layout ----
  for (int i = tid; i < 68 * 16; i += 512) {
    int r = i >> 4, co = (i & 15) << 3;
    int t = t0 - 2 + r;
    f32x4 v0 = {0.f, 0.f, 0.f, 0.f}, v1 = v0;
    if (t >= 0 && t < T) {
      const f32x4* p = reinterpret_cast<const f32x4*>(x + ((size_t)(b * T + t)) * C + co);
      v0 = p[0]; v1 = p[1];
    }
    short8 s;
    s[0] = (short)bfb(v0[0]); s[1] = (short)bfb(v0[1]); s[2] = (short)bfb(v0[2]); s[3] = (short)bfb(v0[3]);
    s[4] = (short)bfb(v1[0]); s[5] = (short)bfb(v1[1]); s[6] = (short)bfb(v1[2]); s[7] = (short)bfb(v1[3]);
    *reinterpret_cast<short8*>(xs + r * XPITCH + co) = s;
  }
  __syncthreads();

  f32x4 accF[4], accZ[4];
#pragma unroll
  for (int mf = 0; mf < 4; ++mf) { accF[mf] = {0.f,0.f,0.f,0.f}; accZ[mf] = {0.f,0.f,0.f,0.f}; }

  const char* xsb = reinterpret_cast<const char*>(xs);
  const short8* wb = reinterpret_cast<const short8*>(Wfrag) + (wid * 128 + lane * 2);
  const int abase = lrow * 272 + lg * 16;

  // ---- software-pipelined K-loop (sched_barrier-pinned) ----
  short8 wf[4], wz[4], av[2][4];
#pragma unroll
  for (int p = 0; p < 3; ++p) {            // weights for kk=0,1,2
    wf[p] = wb[p * 1024];
    wz[p] = wb[p * 1024 + 1];
  }
#pragma unroll
  for (int mf = 0; mf < 4; ++mf)           // a-frags for kk=0 (k=0, cq=0)
    av[0][mf] = *reinterpret_cast<const short8*>(xsb + (abase + (mf * 16) * 272));

#pragma unroll
  for (int kk = 0; kk < NKK; ++kk) {
    __builtin_amdgcn_sched_barrier(0);     // fence: loads below stay below MFMAs above
    if (kk + 3 < NKK) {                    // weight prefetch, 3 iters ahead
      const int o = (kk + 3) * 1024;
      wf[(kk + 3) & 3] = wb[o];
      wz[(kk + 3) & 3] = wb[o + 1];
    }
    if (kk + 1 < NKK) {                    // a-frag prefetch, 1 iter ahead
      const int k1 = (kk + 1) >> 2;        // compile-time
      const int cq1 = ((kk + 1) & 3) << 6; // compile-time
#pragma unroll
      for (int mf = 0; mf < 4; ++mf)
        av[(kk + 1) & 1][mf] =
            *reinterpret_cast<const short8*>(xsb + (abase + (mf * 16 + k1) * 272 + cq1));
    }
    __builtin_amdgcn_sched_barrier(0);     // fence: loads cannot sink past MFMAs below
#pragma unroll
    for (int mf = 0; mf < 4; ++mf) {
      accF[mf] = __builtin_amdgcn_mfma_f32_16x16x32_bf16(av[kk & 1][mf], wf[kk & 3], accF[mf], 0, 0, 0);
      accZ[mf] = __builtin_amdgcn_mfma_f32_16x16x32_bf16(av[kk & 1][mf], wz[kk & 3], accZ[mf], 0, 0, 0);
    }
  }

  // ---- epilogue: FG stores + chunk summary (incremental, no arrays) ----
  const int cblk = blockIdx.x;
  const int h = wid * 16 + lrow;
  const float biasF = fb[h], biasZ = zb[h];
  float cP = 1.f, cQ = 0.f, cFl = 1.f;
#pragma unroll
  for (int mf = 0; mf < 4; ++mf) {
    float y = 0.f, P = 1.f, prevF = 1.f;
#pragma unroll
    for (int j = 0; j < 4; ++j) {
      int m = mf * 16 + lg * 4 + j;
      int s = t0 + m + 1;                       // gate-slot index
      float rf = accF[mf][j] + biasF;
      float rz = accZ[mf][j] + biasZ;
      float F = sigmoidf(rf);
      float G = sigmoidf(rz) * (1.0f - F);
      FG[(size_t)(b * TP1 + s) * H + h] = bfb(F) | (bfb(G) << 16);
      if (j == 0) { y = G; P = 1.f; }
      else { P *= prevF; y = fmaf(prevF, y, G); }
      prevF = F;
    }
    // compose across lg (4 groups of 4 rows) — 2-level tree, valid on lg==0
    float tP = P, tQ = y, tFl = prevF;
    {
      float pP = __shfl(tP, lane + 16, 64);
      float pQ = __shfl(tQ, lane + 16, 64);
      float pF = __shfl(tFl, lane + 16, 64);
      compose(tP, tQ, tFl, pP, pQ, pF);
      pP = __shfl(tP, lane + 32, 64);
      pQ = __shfl(tQ, lane + 32, 64);
      pF = __shfl(tFl, lane + 32, 64);
      compose(tP, tQ, tFl, pP, pQ, pF);
    }
    if (mf == 0) { cP = tP; cQ = tQ; cFl = tFl; }
    else compose(cP, cQ, cFl, tP, tQ, tFl);
  }
  if (lg == 0) {
    int sidx = cblk * NSER + b * H + h;
    sumP[sidx] = cP;
    sumQ[sidx] = cQ;
  }
}

// ---------------------------------------------------------------------------
// scanB: init row (slot 0) + sequential chain over chunk summaries.
// Only 2048 threads exist (no TLP to hide latency) -> batch 8 iterations'
// independent loads ahead of the serial compose chain: 24 loads in flight,
// exposed chain latency / 8. cin aliases sumP (read-before-write, group-wise
// safe: each thread touches only its own series column).
__global__ void scanB_kernel(const float* __restrict__ init,
                             const unsigned* __restrict__ FG_r,
                             unsigned* __restrict__ FG_w,
                             const float* __restrict__ sumQ,
                             float* __restrict__ sumP_cin,   // in: P*, out: cin
                             float* __restrict__ out) {
  int g = blockIdx.x * blockDim.x + threadIdx.x;   // 0..NSER-1 = b*128+h
  int b = g >> 7, h = g & (H - 1);
  float rf = init[g];
  float rz = init[NSER + g];
  float F0 = sigmoidf(rf), z = sigmoidf(rz);
  float G0 = z * (1.0f - F0);
  size_t base = (size_t)b * TP1 * H + h;
  FG_w[base] = bfb(F0) | (bfb(G0) << 16);
  out[base] = G0;
  float y = G0;        // y[0]
  float Fp = F0;       // F[slot 64j] entering group
  for (int j0 = 0; j0 < NCH; j0 += 8) {
    float ps[8], qs[8], fl[8];
#pragma unroll
    for (int u = 0; u < 8; ++u) {
      int sidx = (j0 + u) * NSER + g;
      ps[u] = sumP_cin[sidx];
      qs[u] = sumQ[sidx];
      int jn = j0 + u + 1;
      fl[u] = (jn < NCH)
                  ? __uint_as_float(FG_r[base + (size_t)(64 * jn) * H] << 16)
                  : 1.0f;
    }
#pragma unroll
    for (int u = 0; u < 8; ++u) {
      sumP_cin[(j0 + u) * NSER + g] = y;        // cin for chunk j0+u
      y = fmaf(Fp * ps[u], y, qs[u]);           // y[64(j0+u+1)]
      Fp = fl[u];
    }
  }
}

// ---------------------------------------------------------------------------
// scanC: chunk j covers slots [1+64j, 64+64j]; local rescan with carry-in.
// Max TLP form (2048 blocks, 16 waves/CU); r9 proved trading TLP for wider
// per-thread loads loses on this latency-bound loop.
__global__ __launch_bounds__(128)
void scanC_kernel(const unsigned* __restrict__ FG, const float* __restrict__ cin,
                  float* __restrict__ out) {
  const int b = blockIdx.y, j = blockIdx.x, h = threadIdx.x;
  const int s0 = 1 + j * 64;
  float y = cin[j * NSER + b * H + h];
  const size_t base = (size_t)b * TP1 * H + h;
  const unsigned* p = FG + base + (size_t)s0 * H;
  float Fprev = __uint_as_float(p[-H] << 16);     // F[64j]
  float* po = out + base + (size_t)s0 * H;
#pragma unroll 8
  for (int t = 0; t < 64; ++t) {
    unsigned u = *p; p += H;
    float G = __uint_as_float(u & 0xffff0000u);
    y = fmaf(Fprev, y, G);
    Fprev = __uint_as_float(u << 16);
    *po = y; po += H;
  }
}

}  // namespace

// ---------------------------------------------------------------------------
extern "C" void kernel_launch(void* const* d_in, const int* in_sizes, int n_in,
                              void* d_out, int out_size, void* d_ws, size_t ws_size,
                              hipStream_t stream) {
  const float* x    = (const float*)d_in[0];
  const float* init = (const float*)d_in[1];
  const float* zw   = (const float*)d_in[2];
  const float* zb   = (const float*)d_in[3];
  const float* fw   = (const float*)d_in[4];
  const float* fb   = (const float*)d_in[5];
  float* out = (float*)d_out;
  char* ws = (char*)d_ws;

  // ws layout: [0,4N) FG; then sumP (1MB, becomes cin), sumQ (1MB), Wfrag (0.33MB).
  unsigned* FG = (unsigned*)ws;
  float* sumP = (float*)(ws + (size_t)N * 4);
  float* sumQ = sumP + (size_t)NCH * NSER;
  short* Wfrag = (short*)(sumQ + (size_t)NCH * NSER);

  wprep_kernel<<<(WF_ELE + 255) / 256, 256, 0, stream>>>(fw, zw, Wfrag);
  conv_mfma_kernel<<<dim3(NCH, B), 512, 0, stream>>>(x, fb, zb, Wfrag, FG, sumP, sumQ);
  scanB_kernel<<<16, 128, 0, stream>>>(init, FG, FG, sumQ, sumP, out);
  scanC_kernel<<<dim3(NCH, B), 128, 0, stream>>>(FG, sumP, out);
}